// Round 6
// baseline (11172.336 us; speedup 1.0000x reference)
//
#include <hip/hip_runtime.h>
#include <hip/hip_bf16.h>

// ---------------------------------------------------------------------------
// 2-layer tanh RNN + FC head on MI355X (gfx950).
// Round 6: LDS-resident weights (dynamic LDS, 141 KB/WG) — deterministic
// residency after the register-allocator defeats of rounds 3-5. Per-wave
// full-K MFMA (no split-K), barrier-free layer-0 loop, single-line flag polls.
//   B=64 S=512 I=256 H=1024 O=256
//   layer-0: 64 WGs x 64 cols; wave w owns ntile w (16 cols), full K=1024.
//   layer-1: 128 WGs x 32 cols; waves 0,1 = h0_t@Wih1 (off-chain),
//            waves 2,3 = h1_{t-1}@Whh1 (serial chain), combined via
//            parity-double-buffered LDS patch + 1 barrier/step.
// ---------------------------------------------------------------------------

typedef __attribute__((ext_vector_type(4))) float f32x4;
typedef __attribute__((ext_vector_type(8))) short bf16x8;
typedef __attribute__((ext_vector_type(4))) int   i32x4;
typedef __attribute__((ext_vector_type(4))) short s16x4;

#define B_  64
#define S_  512
#define I_  256
#define H_  1024
#define O_  256
#define M_  (B_ * S_)     // 32768
#define SH_ (S_ * H_)     // 524288 (row stride of h-seq / pre in elements)
#define WST 1064          // LDS weight row stride in shorts (1024+40): 532 dwords
                          // ≡ 20 (mod 32) -> uniform bank coverage on b128 reads
#define LDS_BYTES (64 * WST * 2 + 5120)   // 136192 weights + 5120 qp = 141312

static __device__ __forceinline__ unsigned short f2bf(float f) {
  union { float f; unsigned u; } v; v.f = f;
  unsigned r = v.u + 0x7fffu + ((v.u >> 16) & 1u);   // RNE
  return (unsigned short)(r >> 16);
}
static __device__ __forceinline__ float bf2f(unsigned short b) {
  union { unsigned u; float f; } v; v.u = ((unsigned)b) << 16;
  return v.f;
}
static __device__ __forceinline__ float tanh_fast(float x) {
  float e = __expf(2.f * x);
  return 1.f - 2.f / (e + 1.f);
}

// Full-K (1024) dot for one 16x16 ntile: 32 MFMAs, 4 independent accumulator
// chains for ILP, A from global (h slice), B from LDS (resident weights).
static __device__ __forceinline__ f32x4 dot1024(const unsigned short* hp,
                                                const unsigned short* bs) {
  f32x4 a0 = {}, a1 = {}, a2 = {}, a3 = {};
#pragma unroll 8
  for (int kk = 0; kk < 32; kk += 4) {
    a0 = __builtin_amdgcn_mfma_f32_16x16x32_bf16(
        *(const bf16x8*)(hp + (kk + 0) * 32), *(const bf16x8*)(bs + (kk + 0) * 32), a0, 0, 0, 0);
    a1 = __builtin_amdgcn_mfma_f32_16x16x32_bf16(
        *(const bf16x8*)(hp + (kk + 1) * 32), *(const bf16x8*)(bs + (kk + 1) * 32), a1, 0, 0, 0);
    a2 = __builtin_amdgcn_mfma_f32_16x16x32_bf16(
        *(const bf16x8*)(hp + (kk + 2) * 32), *(const bf16x8*)(bs + (kk + 2) * 32), a2, 0, 0, 0);
    a3 = __builtin_amdgcn_mfma_f32_16x16x32_bf16(
        *(const bf16x8*)(hp + (kk + 3) * 32), *(const bf16x8*)(bs + (kk + 3) * 32), a3, 0, 0, 0);
  }
  f32x4 s;
#pragma unroll
  for (int r = 0; r < 4; ++r) s[r] = a0[r] + a1[r] + a2[r] + a3[r];
  return s;
}

// ---------------- f32 -> bf16 conversion (vectorized) ----------------------
__global__ void cvt_bf16(const float* __restrict__ src,
                         unsigned short* __restrict__ dst, int n4) {
  int i = blockIdx.x * blockDim.x + threadIdx.x;
  if (i < n4) {
    f32x4 v = ((const f32x4*)src)[i];
    s16x4 o;
    o[0] = (short)f2bf(v[0]); o[1] = (short)f2bf(v[1]);
    o[2] = (short)f2bf(v[2]); o[3] = (short)f2bf(v[3]);
    ((s16x4*)dst)[i] = o;
  }
}

// ---------------- big MFMA GEMM: C[M,N] = A[M,K]@W[N,K]^T + b1 (+b2) -------
template <bool BF16OUT>
__global__ __launch_bounds__(256)
void gemm_bf16(const unsigned short* __restrict__ A,
               const unsigned short* __restrict__ W,
               const float* __restrict__ b1, const float* __restrict__ b2,
               void* __restrict__ Cv, int Mx, int Nx, int Kx) {
  __shared__ __align__(16) unsigned short As[128 * 40];
  __shared__ __align__(16) unsigned short Bs[128 * 40];
  const int tid  = threadIdx.x;
  const int m0   = blockIdx.y * 128;
  const int n0   = blockIdx.x * 128;
  const int w    = tid >> 6, lane = tid & 63;
  const int quad = lane >> 4, l15 = lane & 15;
  const int wm = (w & 1) * 64, wn = (w >> 1) * 64;

  f32x4 acc[4][4] = {};

  for (int k0 = 0; k0 < Kx; k0 += 32) {
#pragma unroll
    for (int i = 0; i < 2; ++i) {
      int c = tid + i * 256;
      int row = c >> 2, kc = c & 3;
      *(i32x4*)&As[row * 40 + kc * 8] =
          *(const i32x4*)&A[(size_t)(m0 + row) * Kx + k0 + kc * 8];
      *(i32x4*)&Bs[row * 40 + kc * 8] =
          *(const i32x4*)&W[(size_t)(n0 + row) * Kx + k0 + kc * 8];
    }
    __syncthreads();
    bf16x8 af[4], bg[4];
#pragma unroll
    for (int im = 0; im < 4; ++im)
      af[im] = *(const bf16x8*)&As[(wm + im * 16 + l15) * 40 + quad * 8];
#pragma unroll
    for (int in = 0; in < 4; ++in)
      bg[in] = *(const bf16x8*)&Bs[(wn + in * 16 + l15) * 40 + quad * 8];
#pragma unroll
    for (int im = 0; im < 4; ++im)
#pragma unroll
      for (int in = 0; in < 4; ++in)
        acc[im][in] = __builtin_amdgcn_mfma_f32_16x16x32_bf16(
            af[im], bg[in], acc[im][in], 0, 0, 0);
    __syncthreads();
  }

#pragma unroll
  for (int in = 0; in < 4; ++in) {
    int n = n0 + wn + in * 16 + l15;
    float bv = b1 ? b1[n] : 0.f;
    if (b2) bv += b2[n];
#pragma unroll
    for (int im = 0; im < 4; ++im) {
      int mb = m0 + wm + im * 16 + quad * 4;   // C/D: row = quad*4+reg, col = l15
#pragma unroll
      for (int r = 0; r < 4; ++r) {
        float val = acc[im][in][r] + bv;
        size_t o = (size_t)(mb + r) * Nx + n;
        if (BF16OUT) ((unsigned short*)Cv)[o] = f2bf(val);
        else         ((float*)Cv)[o] = val;
      }
    }
  }
}

// ---------------- fused dual-layer persistent recurrence -------------------
// Grid: 192 WGs x 256 thr, dynamic LDS 141312 B (1 WG/CU).
// Flags: per (group,step) a 64-B line of counters. F0[g][t][0..3]: L0 wave w
// of each of 16 WGs adds 1 to word w (target 16). F1[g][t][0..1]: L1 waves
// 2,3 of each of 32 WGs add 1 (target 32). Producers release-add (drains the
// wave's agent h-stores first); consumers poll one coalesced line relaxed,
// then agent-acquire fence. All h/flag addresses are fresh per t.
__global__ __launch_bounds__(256)
void rnn_fused(const unsigned short* __restrict__ Whh0,   // [H,H] bf16
               const unsigned short* __restrict__ Wih1,   // [H,H] bf16
               const unsigned short* __restrict__ Whh1,   // [H,H] bf16
               const unsigned short* __restrict__ pre0,   // [B,S,H] bf16
               const float* __restrict__ b_ih_1,
               const float* __restrict__ b_hh_1,
               unsigned short* __restrict__ h0seq,        // [B,S,H] bf16
               unsigned short* __restrict__ h1seq,        // [B,S,H] bf16
               unsigned int* __restrict__ flags)          // [2][4][S][16] zeroed
{
  extern __shared__ __align__(16) char smem[];
  unsigned short* Ws = (unsigned short*)smem;              // 64 cols x WST
  float* qp = (float*)(smem + (size_t)64 * WST * 2);       // [2][2][16][20] f32

  const int bx   = blockIdx.x;
  const int tid  = threadIdx.x;
  const int w    = tid >> 6;
  const int lane = tid & 63;
  const int quad = lane >> 4, l15 = lane & 15;

  if (bx < 64) {
    // ================= layer 0: 64 WGs, 64 cols, no barriers in loop =======
    const int g = bx >> 4, j = bx & 15, n0 = j * 64;
    unsigned int* const f0c = flags + (size_t)g * S_ * 16;

    for (int idx = tid; idx < 64 * 128; idx += 256) {      // stage Whh0 slice
      int col = idx >> 7, kc = idx & 127;
      *(i32x4*)&Ws[col * WST + kc * 8] =
          *(const i32x4*)&Whh0[(size_t)(n0 + col) * H_ + kc * 8];
    }
    __syncthreads();

    const unsigned short* const bs = Ws + (w * 16 + l15) * WST + quad * 8;

    for (int t = 0; t < S_; ++t) {
      float pv[4];                                         // pre0 prefetch
      const unsigned short* pp = pre0 + (size_t)(g * 16 + quad * 4) * SH_ +
                                 (size_t)t * H_ + n0 + w * 16 + l15;
#pragma unroll
      for (int r = 0; r < 4; ++r) pv[r] = bf2f(pp[(size_t)r * SH_]);

      f32x4 acc = {};
      if (t > 0) {
        const unsigned int* fp = f0c + (size_t)(t - 1) * 16 + (lane & 3);
        unsigned v;
        do {
          v = __hip_atomic_load(fp, __ATOMIC_RELAXED, __HIP_MEMORY_SCOPE_AGENT);
        } while (!__all(v >= 16u));
        __builtin_amdgcn_fence(__ATOMIC_ACQUIRE, "agent");
        const unsigned short* hp = h0seq + (size_t)(g * 16 + l15) * SH_ +
                                   (size_t)(t - 1) * H_ + quad * 8;
        acc = dot1024(hp, bs);
      }
#pragma unroll
      for (int r = 0; r < 4; ++r) {
        unsigned short hb = f2bf(tanh_fast(pv[r] + acc[r]));
        size_t o = (size_t)(g * 16 + quad * 4 + r) * SH_ + (size_t)t * H_ +
                   n0 + w * 16 + l15;
        __hip_atomic_store(&h0seq[o], hb, __ATOMIC_RELAXED,
                           __HIP_MEMORY_SCOPE_AGENT);
      }
      if (lane == 0)   // release drains this wave's h stores first
        __hip_atomic_fetch_add(&f0c[(size_t)t * 16 + w], 1u,
                               __ATOMIC_RELEASE, __HIP_MEMORY_SCOPE_AGENT);
    }
  } else {
    // ================= layer 1: 128 WGs, 32 cols ==========================
    const int id = bx - 64, g = id >> 5, j = id & 31, n0 = j * 32;
    unsigned int* const f0c = flags + (size_t)g * S_ * 16;
    unsigned int* const f1c = flags + (size_t)4 * S_ * 16 + (size_t)g * S_ * 16;

    for (int idx = tid; idx < 64 * 128; idx += 256) {      // stage Wi | Wr
      int col = idx >> 7, kc = idx & 127;
      const unsigned short* src = (col < 32)
          ? &Wih1[(size_t)(n0 + col) * H_ + kc * 8]
          : &Whh1[(size_t)(n0 + col - 32) * H_ + kc * 8];
      *(i32x4*)&Ws[col * WST + kc * 8] = *(const i32x4*)src;
    }
    __syncthreads();

    if (w < 2) {
      // waves 0,1: input projection h0_t @ Wih1 (ntile w) — off the f1 chain
      const unsigned short* const bs = Ws + (w * 16 + l15) * WST + quad * 8;
      for (int t = 0; t < S_; ++t) {
        const unsigned int* fp = f0c + (size_t)t * 16 + (lane & 3);
        unsigned v;
        do {
          v = __hip_atomic_load(fp, __ATOMIC_RELAXED, __HIP_MEMORY_SCOPE_AGENT);
        } while (!__all(v >= 16u));
        __builtin_amdgcn_fence(__ATOMIC_ACQUIRE, "agent");
        const unsigned short* hp = h0seq + (size_t)(g * 16 + l15) * SH_ +
                                   (size_t)t * H_ + quad * 8;
        f32x4 acc = dot1024(hp, bs);
        *(f32x4*)&qp[(((size_t)(t & 1) * 2 + w) * 16 + l15) * 20 + quad * 4] = acc;
        __syncthreads();
      }
    } else {
      // waves 2,3: recurrence h1_{t-1} @ Whh1 (ntile w-2) — the serial chain
      const unsigned short* const bs =
          Ws + (32 + (w - 2) * 16 + l15) * WST + quad * 8;
      const int n = n0 + (w - 2) * 16 + l15;
      const float bias = b_ih_1[n] + b_hh_1[n];
      for (int t = 0; t < S_; ++t) {
        f32x4 acc = {};
        if (t > 0) {
          const unsigned int* fp = f1c + (size_t)(t - 1) * 16 + (lane & 1);
          unsigned v;
          do {
            v = __hip_atomic_load(fp, __ATOMIC_RELAXED, __HIP_MEMORY_SCOPE_AGENT);
          } while (!__all(v >= 32u));
          __builtin_amdgcn_fence(__ATOMIC_ACQUIRE, "agent");
          const unsigned short* hp = h1seq + (size_t)(g * 16 + l15) * SH_ +
                                     (size_t)(t - 1) * H_ + quad * 8;
          acc = dot1024(hp, bs);
        }
        __syncthreads();   // pairs with waves 0,1's qp[t&1] write
        f32x4 p = *(const f32x4*)
            &qp[(((size_t)(t & 1) * 2 + (w - 2)) * 16 + l15) * 20 + quad * 4];
#pragma unroll
        for (int r = 0; r < 4; ++r) {
          unsigned short hb = f2bf(tanh_fast(bias + p[r] + acc[r]));
          size_t o = (size_t)(g * 16 + quad * 4 + r) * SH_ + (size_t)t * H_ +
                     n0 + (w - 2) * 16 + l15;
          __hip_atomic_store(&h1seq[o], hb, __ATOMIC_RELAXED,
                             __HIP_MEMORY_SCOPE_AGENT);
        }
        if (lane == 0)
          __hip_atomic_fetch_add(&f1c[(size_t)t * 16 + (w - 2)], 1u,
                                 __ATOMIC_RELEASE, __HIP_MEMORY_SCOPE_AGENT);
      }
    }
  }
}

// ---------------------------------------------------------------------------
extern "C" void kernel_launch(void* const* d_in, const int* in_sizes, int n_in,
                              void* d_out, int out_size, void* d_ws, size_t ws_size,
                              hipStream_t stream) {
  const float* x      = (const float*)d_in[0];
  const float* W_ih_0 = (const float*)d_in[1];
  const float* W_hh_0 = (const float*)d_in[2];
  const float* b_ih_0 = (const float*)d_in[3];
  const float* b_hh_0 = (const float*)d_in[4];
  const float* W_ih_1 = (const float*)d_in[5];
  const float* W_hh_1 = (const float*)d_in[6];
  const float* b_ih_1 = (const float*)d_in[7];
  const float* b_hh_1 = (const float*)d_in[8];
  const float* fc_w   = (const float*)d_in[9];
  const float* fc_b   = (const float*)d_in[10];
  float* out = (float*)d_out;

  char* ws = (char*)d_ws;
  size_t off = 0;
  auto alloc = [&](size_t bytes) { char* p = ws + off; off += (bytes + 255) & ~(size_t)255; return p; };
  unsigned short* xb    = (unsigned short*)alloc((size_t)M_ * I_ * 2);   // 16.8 MB
  unsigned short* wih0b = (unsigned short*)alloc((size_t)H_ * I_ * 2);
  unsigned short* whh0b = (unsigned short*)alloc((size_t)H_ * H_ * 2);
  unsigned short* wih1b = (unsigned short*)alloc((size_t)H_ * H_ * 2);
  unsigned short* whh1b = (unsigned short*)alloc((size_t)H_ * H_ * 2);
  unsigned short* fcwb  = (unsigned short*)alloc((size_t)O_ * H_ * 2);
  const size_t flagBytes = (size_t)2 * 4 * S_ * 16 * 4;                  // 256 KB
  unsigned int*   flags = (unsigned int*)alloc(flagBytes);
  unsigned short* pre0b = (unsigned short*)alloc((size_t)M_ * H_ * 2);   // 67 MB
  unsigned short* h0seq = (unsigned short*)alloc((size_t)M_ * H_ * 2);   // 67 MB
  unsigned short* h1seq = (unsigned short*)alloc((size_t)M_ * H_ * 2);   // 67 MB

  hipMemsetAsync(flags, 0, flagBytes, stream);

  auto cvt = [&](const float* s, unsigned short* d, int n) {
    int n4 = n / 4;
    cvt_bf16<<<(n4 + 255) / 256, 256, 0, stream>>>(s, d, n4);
  };
  cvt(x,      xb,    M_ * I_);
  cvt(W_ih_0, wih0b, H_ * I_);
  cvt(W_hh_0, whh0b, H_ * H_);
  cvt(W_ih_1, wih1b, H_ * H_);
  cvt(W_hh_1, whh1b, H_ * H_);
  cvt(fc_w,   fcwb,  O_ * H_);

  // pre0 = x @ W_ih0^T + b_ih0 + b_hh0  (bf16 out)
  gemm_bf16<true><<<dim3(H_ / 128, M_ / 128), 256, 0, stream>>>(
      xb, wih0b, b_ih_0, b_hh_0, pre0b, M_, H_, I_);

  // fused dual-layer recurrence, LDS-resident weights (141 KB dynamic LDS)
  hipFuncSetAttribute((const void*)rnn_fused,
                      hipFuncAttributeMaxDynamicSharedMemorySize, LDS_BYTES);
  rnn_fused<<<192, 256, LDS_BYTES, stream>>>(whh0b, wih1b, whh1b, pre0b,
                                             b_ih_1, b_hh_1, h0seq, h1seq,
                                             flags);

  // FC head
  gemm_bf16<false><<<dim3(O_ / 128, M_ / 128), 256, 0, stream>>>(
      h1seq, fcwb, fc_b, nullptr, out, M_, O_, H_);
}